// Round 14
// baseline (670.739 us; speedup 1.0000x reference)
//
#include <hip/hip_runtime.h>
#include <hip/hip_bf16.h>
#include <stdint.h>

#define BNEPS 1e-5f

typedef __bf16 bf16x8 __attribute__((ext_vector_type(8)));
typedef float f32x4 __attribute__((ext_vector_type(4)));
typedef unsigned short ushort8 __attribute__((ext_vector_type(8)));

__device__ __forceinline__ float gelu_f(float x) {
    return 0.5f * x * (1.0f + erff(x * 0.70710678118654752440f));
}
__device__ __forceinline__ float sigmoid_f(float x) {
    return 1.0f / (1.0f + __expf(-x));
}
__device__ __forceinline__ float tanh_f(float x) {
    x = fminf(fmaxf(x, -15.0f), 15.0f);
    const float e = __expf(2.0f * x);
    return (e - 1.0f) / (e + 1.0f);
}
__device__ __forceinline__ float bf2f(unsigned short u) {
    return __uint_as_float(((unsigned)u) << 16);
}
__device__ __forceinline__ void async16(const void* g, void* l) {
    __builtin_amdgcn_global_load_lds(
        (const __attribute__((address_space(1))) void*)g,
        (__attribute__((address_space(3))) void*)l,
        16, 0, 0);
}

// ---------------- stem: conv0 4x4/4 + BN0 + GELU -> y0 bf16 [32][256][8][256]
__global__ __launch_bounds__(256)
void stem_kernel(const float* __restrict__ x, const float* __restrict__ w,
                 const float* __restrict__ cb,
                 const float* __restrict__ bg, const float* __restrict__ bb,
                 const float* __restrict__ bm, const float* __restrict__ bv,
                 __hip_bfloat16* __restrict__ y0)
{
    __shared__ float sw[64 * 48];
    const int ho = blockIdx.x, b = blockIdx.y, co0 = blockIdx.z * 64;
    const int wo = threadIdx.x;
    for (int i = threadIdx.x; i < 64 * 48; i += 256) sw[i] = w[co0 * 48 + i];
    float p[48];
    #pragma unroll
    for (int c = 0; c < 3; ++c)
        #pragma unroll
        for (int kh = 0; kh < 4; ++kh) {
            const float4 q = *reinterpret_cast<const float4*>(
                &x[((size_t)(b * 3 + c) * 32 + ho * 4 + kh) * 1024 + wo * 4]);
            p[c * 16 + kh * 4 + 0] = q.x;
            p[c * 16 + kh * 4 + 1] = q.y;
            p[c * 16 + kh * 4 + 2] = q.z;
            p[c * 16 + kh * 4 + 3] = q.w;
        }
    __syncthreads();
    for (int c2 = 0; c2 < 64; ++c2) {
        const int co = co0 + c2;
        const float* wp = &sw[c2 * 48];
        float a0 = 0.f, a1 = 0.f, a2 = 0.f, a3 = 0.f;
        #pragma unroll
        for (int i = 0; i < 12; ++i) {
            const float4 wq = *reinterpret_cast<const float4*>(&wp[i * 4]);
            a0 += wq.x * p[i * 4 + 0];
            a1 += wq.y * p[i * 4 + 1];
            a2 += wq.z * p[i * 4 + 2];
            a3 += wq.w * p[i * 4 + 3];
        }
        const float acc = (a0 + a1) + (a2 + a3) + cb[co];
        const float sc = bg[co] / sqrtf(bv[co] + BNEPS);
        const float val = (acc - bm[co]) * sc + bb[co];
        y0[((size_t)(b * 256 + co) * 8 + ho) * 256 + wo] = __float2bfloat16(gelu_f(val));
    }
}

// ---------------- depthwise 3x3 + BN1 + GELU + residual: y0 bf16 -> y1 bf16 [b][c][8][256]
__global__ __launch_bounds__(256)
void dw_kernel(const __hip_bfloat16* __restrict__ y0, const float* __restrict__ dww,
               const float* __restrict__ dwb,
               const float* __restrict__ bg, const float* __restrict__ bb,
               const float* __restrict__ bm, const float* __restrict__ bv,
               __hip_bfloat16* __restrict__ y1)
{
    __shared__ float tile[8][258];
    const int c = blockIdx.x, b = blockIdx.y, t = threadIdx.x;
    const __hip_bfloat16* src = &y0[(size_t)(b * 256 + c) * 2048];
    {   // vectorized bf16x8 load: thread t covers flat elems [t*8, t*8+8)
        const ushort8 v = *reinterpret_cast<const ushort8*>(&src[t * 8]);
        const int r = t >> 5, c0 = (t & 31) * 8;
        #pragma unroll
        for (int i = 0; i < 8; ++i) tile[r][1 + c0 + i] = bf2f(v[i]);
    }
    if (t < 8) { tile[t][0] = 0.f; tile[t][257] = 0.f; }
    float w9[9];
    #pragma unroll
    for (int i = 0; i < 9; ++i) w9[i] = dww[c * 9 + i];
    const float bias = dwb[c];
    const float sc = bg[c] / sqrtf(bv[c] + BNEPS);
    const float sb = bb[c] - bm[c] * sc;
    __syncthreads();
    __hip_bfloat16* dst = &y1[(size_t)(b * 256 + c) * 2048];
    #pragma unroll
    for (int r = 0; r < 8; ++r) {
        float acc = bias;
        #pragma unroll
        for (int kh = 0; kh < 3; ++kh) {
            const int rr = r + kh - 1;
            if (rr < 0 || rr > 7) continue;
            acc += w9[kh * 3 + 0] * tile[rr][t] + w9[kh * 3 + 1] * tile[rr][t + 1]
                 + w9[kh * 3 + 2] * tile[rr][t + 2];
        }
        const float val = gelu_f(acc * sc + sb);
        dst[r * 256 + t] = __float2bfloat16(tile[r][t + 1] + val);
    }
}

// ---------------- pointwise GEMM with in-kernel B transpose (reg-staged).
// C[co][pos] = sum_ci W[co][ci] * y1[b][ci][pos]; BM=BN=128, BK=32, 4 waves.
// sB layout is the verified [128 pos][32 ci] (round-2); built by reg-staged
// transposed writes: each thread loads two 16B runs from adjacent ci rows,
// packs ci/ci+1 into u32, 8x ds_write_b32. Fragments/MFMA/epilogue unchanged.
// Epilogue: bias+BN2+GELU -> y0 bf16 [b][co][hw].
__global__ __launch_bounds__(256)
void gemm_pw_kernel(const __hip_bfloat16* __restrict__ A,
                    const __hip_bfloat16* __restrict__ y1,
                    __hip_bfloat16* __restrict__ out,
                    const float* __restrict__ q0, const float* __restrict__ q1,
                    const float* __restrict__ q2, const float* __restrict__ q3,
                    const float* __restrict__ q4)
{
    __shared__ __hip_bfloat16 sA[2][4096];
    __shared__ __hip_bfloat16 sB[2][4096];
    const int tid = threadIdx.x;
    const int wave = tid >> 6, lane = tid & 63;
    const int m0 = blockIdx.y * 128, n0 = blockIdx.x * 128;
    const int b = n0 >> 11, hw0 = n0 & 2047;
    const __hip_bfloat16* ysrc = y1 + (size_t)b * 524288;   // [256 ci][2048 pos]

    const int ci2 = tid & 15, pos8 = tid >> 4;   // B-staging coords

    auto stageA = [&](int buf, int kt) {
        const int k0 = kt << 5;
        #pragma unroll
        for (int r = 0; r < 2; ++r) {
            const int e = wave * 1024 + r * 512 + lane * 8;
            const int row = e >> 5, ko = e & 31;
            async16(&A[(size_t)(m0 + row) * 256 + k0 + ko], &sA[buf][wave * 1024 + r * 512]);
        }
    };
    auto stageB = [&](int buf, int kt) {
        const int ci0 = kt << 5;
        const ushort8 u0 = *reinterpret_cast<const ushort8*>(
            &ysrc[(size_t)(ci0 + 2 * ci2) * 2048 + hw0 + pos8 * 8]);
        const ushort8 u1 = *reinterpret_cast<const ushort8*>(
            &ysrc[(size_t)(ci0 + 2 * ci2 + 1) * 2048 + hw0 + pos8 * 8]);
        #pragma unroll
        for (int j = 0; j < 8; ++j) {
            const unsigned pk = (unsigned)u0[j] | ((unsigned)u1[j] << 16);
            *reinterpret_cast<unsigned*>(&sB[buf][(pos8 * 8 + j) * 32 + 2 * ci2]) = pk;
        }
    };

    f32x4 acc[4][4];
    #pragma unroll
    for (int i = 0; i < 4; ++i)
        #pragma unroll
        for (int j = 0; j < 4; ++j) acc[i][j] = (f32x4){0.f, 0.f, 0.f, 0.f};

    stageA(0, 0); stageB(0, 0);
    const int wm = wave >> 1, wn = wave & 1;
    const int lrow = lane & 15, lgrp = lane >> 4;
    int cur = 0;
    for (int kt = 0; kt < 8; ++kt) {
        __syncthreads();   // drains vmcnt (A) + lgkm (B writes): buf[cur] ready
        if (kt + 1 < 8) { stageA(cur ^ 1, kt + 1); stageB(cur ^ 1, kt + 1); }
        bf16x8 av[4], bw[4];
        #pragma unroll
        for (int i = 0; i < 4; ++i) {
            av[i] = *reinterpret_cast<const bf16x8*>(&sA[cur][(wm * 64 + i * 16 + lrow) * 32 + lgrp * 8]);
            bw[i] = *reinterpret_cast<const bf16x8*>(&sB[cur][(wn * 64 + i * 16 + lrow) * 32 + lgrp * 8]);
        }
        #pragma unroll
        for (int mi = 0; mi < 4; ++mi)
            #pragma unroll
            for (int ni = 0; ni < 4; ++ni)
                acc[mi][ni] = __builtin_amdgcn_mfma_f32_16x16x32_bf16(av[mi], bw[ni], acc[mi][ni], 0, 0, 0);
        cur ^= 1;
    }

    #pragma unroll
    for (int mi = 0; mi < 4; ++mi) {
        const int rowb = m0 + wm * 64 + mi * 16 + lgrp * 4;
        #pragma unroll
        for (int ni = 0; ni < 4; ++ni) {
            const int hw = hw0 + wn * 64 + ni * 16 + lrow;
            #pragma unroll
            for (int r = 0; r < 4; ++r) {
                const float v = acc[mi][ni][r];
                const int co = rowb + r;
                const float sc = q1[co] / sqrtf(q4[co] + BNEPS);
                const float sb = q2[co] - q3[co] * sc;
                const float val = gelu_f((v + q0[co]) * sc + sb);
                out[((size_t)(b * 256 + co)) * 2048 + hw] = __float2bfloat16(val);
            }
        }
    }
}

// ---------------- FC GEMM: exact round-2 structure (866 TF verified).
__global__ __launch_bounds__(512, 2)
void gemm_fc_kernel(const __hip_bfloat16* __restrict__ A,
                    const __hip_bfloat16* __restrict__ Bt,
                    const float* __restrict__ fcb,
                    float* __restrict__ out)
{
    constexpr int K = 2048, NT = 64, NTILE = 26;
    __shared__ __hip_bfloat16 smem[49152];
    const int tid = threadIdx.x, wave = tid >> 6, lane = tid & 63;
    const int wm = wave >> 2, wn = wave & 3;
    const int r = lane & 15, g = lane >> 4;
    const int swzk = (g ^ ((r >> 1) & 3)) * 8;

    const int bid = blockIdx.x;
    const int swz = (bid & 7) * 104 + (bid >> 3);
    const int m0 = (swz / NTILE) * 256;
    const int n0 = (swz % NTILE) * 256;

    auto stageA = [&](int buf, int kt) {
        #pragma unroll
        for (int r2 = 0; r2 < 2; ++r2) {
            const int e = wave * 128 + r2 * 64 + lane;
            const int row = e >> 2, slot = e & 3;
            const int kg = slot ^ ((row >> 1) & 3);
            async16(&A[(size_t)(m0 + row) * K + kt * 32 + kg * 8],
                    &smem[buf * 8192 + wave * 1024 + r2 * 512]);
        }
    };
    auto stageB = [&](int buf, int kt) {
        #pragma unroll
        for (int r2 = 0; r2 < 2; ++r2) {
            const int e = wave * 128 + r2 * 64 + lane;
            const int row = e >> 2, slot = e & 3;
            const int kg = slot ^ ((row >> 1) & 3);
            async16(&Bt[(size_t)(n0 + row) * K + kt * 32 + kg * 8],
                    &smem[24576 + buf * 8192 + wave * 1024 + r2 * 512]);
        }
    };

    f32x4 acc[8][4];
    #pragma unroll
    for (int i = 0; i < 8; ++i)
        #pragma unroll
        for (int j = 0; j < 4; ++j) acc[i][j] = (f32x4){0.f, 0.f, 0.f, 0.f};

    stageA(0, 0); stageB(0, 0);
    stageA(1, 1); stageB(1, 1);

    int bc = 0;
    for (int kt = 0; kt < NT; ++kt) {
        if (kt < NT - 1) asm volatile("s_waitcnt vmcnt(4)" ::: "memory");
        else             asm volatile("s_waitcnt vmcnt(0)" ::: "memory");
        asm volatile("s_barrier" ::: "memory");

        const int bn = (bc + 2 >= 3) ? bc - 1 : bc + 2;
        if (kt + 2 < NT) stageA(bn, kt + 2);

        const __hip_bfloat16* pA = &smem[bc * 8192];
        const __hip_bfloat16* pB = &smem[24576 + bc * 8192];
        bf16x8 av[8];
        #pragma unroll
        for (int mi = 0; mi < 8; ++mi)
            av[mi] = *reinterpret_cast<const bf16x8*>(&pA[(wm * 128 + mi * 16 + r) * 32 + swzk]);
        bf16x8 b0 = *reinterpret_cast<const bf16x8*>(&pB[(wn * 64 + 0 * 16 + r) * 32 + swzk]);
        bf16x8 b1 = *reinterpret_cast<const bf16x8*>(&pB[(wn * 64 + 1 * 16 + r) * 32 + swzk]);

        __builtin_amdgcn_s_setprio(1);
        #pragma unroll
        for (int mi = 0; mi < 8; ++mi) {
            acc[mi][0] = __builtin_amdgcn_mfma_f32_16x16x32_bf16(av[mi], b0, acc[mi][0], 0, 0, 0);
            acc[mi][1] = __builtin_amdgcn_mfma_f32_16x16x32_bf16(av[mi], b1, acc[mi][1], 0, 0, 0);
        }
        __builtin_amdgcn_s_setprio(0);

        if (kt + 2 < NT) stageB(bn, kt + 2);
        bf16x8 b2 = *reinterpret_cast<const bf16x8*>(&pB[(wn * 64 + 2 * 16 + r) * 32 + swzk]);
        bf16x8 b3 = *reinterpret_cast<const bf16x8*>(&pB[(wn * 64 + 3 * 16 + r) * 32 + swzk]);

        __builtin_amdgcn_s_setprio(1);
        #pragma unroll
        for (int mi = 0; mi < 8; ++mi) {
            acc[mi][2] = __builtin_amdgcn_mfma_f32_16x16x32_bf16(av[mi], b2, acc[mi][2], 0, 0, 0);
            acc[mi][3] = __builtin_amdgcn_mfma_f32_16x16x32_bf16(av[mi], b3, acc[mi][3], 0, 0, 0);
        }
        __builtin_amdgcn_s_setprio(0);

        bc = (bc == 2) ? 0 : bc + 1;
    }

    #pragma unroll
    for (int mi = 0; mi < 8; ++mi) {
        const int rowb = m0 + wm * 128 + mi * 16 + g * 4;
        #pragma unroll
        for (int ni = 0; ni < 4; ++ni) {
            const int col = n0 + wn * 64 + ni * 16 + r;
            if (col < 6625) {
                const float bb = fcb[col];
                #pragma unroll
                for (int rr = 0; rr < 4; ++rr)
                    out[(size_t)(rowb + rr) * 6625 + col] = acc[mi][ni][rr] + bb;
            }
        }
    }
}

// ---------------- ConvLSTM scan over t=channel (256 steps), y0 bf16 input.
// Write path: buffer 8 t-steps in a wave-local LDS 8x8 transpose, then one
// coalesced bf16x8 store per lane (128B runs per 8-lane group). Values and
// compute order identical to the scalar-store version.
__global__ __launch_bounds__(256)
void lstm_kernel(const __hip_bfloat16* __restrict__ y, const float* __restrict__ lw,
                 const float* __restrict__ lb, __hip_bfloat16* __restrict__ Am)
{
    __shared__ __hip_bfloat16 hb[2048];                 // [32 lpos][8 j][8 f]
    const int tid = threadIdx.x;
    const int gid = blockIdx.x * 256 + tid;             // 65536 threads
    const int f = gid & 7, pos = gid >> 3;
    const int l = pos & 255, b = pos >> 8;
    const int lpos = tid >> 3;                          // pos within block
    float W[4][16], bias[4];
    #pragma unroll
    for (int g = 0; g < 4; ++g) {
        #pragma unroll
        for (int j = 0; j < 16; ++j) W[g][j] = lw[(g * 8 + f) * 16 + j];
        bias[g] = lb[g * 8 + f];
    }
    float h = 0.f, c = 0.f;
    const __hip_bfloat16* xb = y + (size_t)b * 524288 + f * 256 + l;  // t-stride 2048
    __hip_bfloat16* ob = Am + (size_t)pos * 2048;
    float xn = __bfloat162float(xb[0]);
    for (int tb = 0; tb < 32; ++tb) {
        #pragma unroll
        for (int j = 0; j < 8; ++j) {
            const int t = tb * 8 + j;
            const float xt = xn;
            if (t < 255) xn = __bfloat162float(xb[(size_t)(t + 1) * 2048]);
            float A0 = bias[0], A1 = bias[1], A2 = bias[2], A3 = bias[3];
            #pragma unroll
            for (int jj = 0; jj < 8; ++jj) {
                const float xj = __shfl(xt, jj, 8);
                const float hj = __shfl(h, jj, 8);
                A0 += W[0][jj] * xj + W[0][8 + jj] * hj;
                A1 += W[1][jj] * xj + W[1][8 + jj] * hj;
                A2 += W[2][jj] * xj + W[2][8 + jj] * hj;
                A3 += W[3][jj] * xj + W[3][8 + jj] * hj;
            }
            c = sigmoid_f(A1) * c + sigmoid_f(A0) * tanh_f(A3);   // af, ai, ag
            h = sigmoid_f(A2) * tanh_f(c);                        // ao
            hb[lpos * 64 + j * 8 + f] = __float2bfloat16(h);
        }
        // wave-local 8x8 transpose readback: lane (lpos, f) reads row j=f
        const bf16x8 vv = *reinterpret_cast<const bf16x8*>(&hb[lpos * 64 + f * 8]);
        *reinterpret_cast<bf16x8*>(&ob[(tb * 8 + f) * 8]) = vv;
    }
}

// ---------------- converters
__global__ void cvt_pww_kernel(const float* __restrict__ w, __hip_bfloat16* __restrict__ o, int n)
{
    const int i = blockIdx.x * 256 + threadIdx.x;
    if (i < n) o[i] = __float2bfloat16(w[i]);
}
__global__ void cvt_fcw_kernel(const float* __restrict__ w, __hip_bfloat16* __restrict__ o)
{
    const size_t i4 = (size_t)blockIdx.x * 256 + threadIdx.x;   // over (6656*2048)/4
    const size_t base = i4 * 4;
    const size_t nrow = base >> 11, k = base & 2047;
    if (nrow < 6625) {
        const float4 q = *reinterpret_cast<const float4*>(&w[nrow * 2048 + k]);
        o[base + 0] = __float2bfloat16(q.x);
        o[base + 1] = __float2bfloat16(q.y);
        o[base + 2] = __float2bfloat16(q.z);
        o[base + 3] = __float2bfloat16(q.w);
    } else {
        o[base + 0] = __float2bfloat16(0.0f);
        o[base + 1] = __float2bfloat16(0.0f);
        o[base + 2] = __float2bfloat16(0.0f);
        o[base + 3] = __float2bfloat16(0.0f);
    }
}

extern "C" void kernel_launch(void* const* d_in, const int* in_sizes, int n_in,
                              void* d_out, int out_size, void* d_ws, size_t ws_size,
                              hipStream_t stream)
{
    const float* x       = (const float*)d_in[0];
    const float* conv0_w = (const float*)d_in[1];
    const float* conv0_b = (const float*)d_in[2];
    const float* bn0_g   = (const float*)d_in[3];
    const float* bn0_b   = (const float*)d_in[4];
    const float* bn0_m   = (const float*)d_in[5];
    const float* bn0_v   = (const float*)d_in[6];
    const float* dw_w    = (const float*)d_in[7];
    const float* dw_b    = (const float*)d_in[8];
    const float* bn1_g   = (const float*)d_in[9];
    const float* bn1_b   = (const float*)d_in[10];
    const float* bn1_m   = (const float*)d_in[11];
    const float* bn1_v   = (const float*)d_in[12];
    const float* pw_w    = (const float*)d_in[13];
    const float* pw_b    = (const float*)d_in[14];
    const float* bn2_g   = (const float*)d_in[15];
    const float* bn2_b   = (const float*)d_in[16];
    const float* bn2_m   = (const float*)d_in[17];
    const float* bn2_v   = (const float*)d_in[18];
    const float* lstm_w  = (const float*)d_in[19];
    const float* lstm_b  = (const float*)d_in[20];
    const float* fc_w    = (const float*)d_in[21];
    const float* fc_b    = (const float*)d_in[22];

    char* ws = (char*)d_ws;
    __hip_bfloat16* y0   = (__hip_bfloat16*)(ws);               // 33,554,432 B
    __hip_bfloat16* y1   = (__hip_bfloat16*)(ws + 33554432);    // 33,554,432 B
    __hip_bfloat16* Am   = (__hip_bfloat16*)(ws + 100663296);   // 33,554,432 B
    __hip_bfloat16* fcwb = (__hip_bfloat16*)(ws + 134217728);   // 27,262,976 B ([6656][2048])
    __hip_bfloat16* pwwb = (__hip_bfloat16*)(ws + 161480704);   //    524,288 B

    stem_kernel<<<dim3(8, 32, 4), 256, 0, stream>>>(
        x, conv0_w, conv0_b, bn0_g, bn0_b, bn0_m, bn0_v, y0);
    cvt_pww_kernel<<<1024, 256, 0, stream>>>(pw_w, pwwb, 262144);
    cvt_fcw_kernel<<<13312, 256, 0, stream>>>(fc_w, fcwb);

    for (int i = 0; i < 4; ++i) {
        dw_kernel<<<dim3(256, 32), 256, 0, stream>>>(
            y0, dw_w + i * 2304, dw_b + i * 256,
            bn1_g + i * 256, bn1_b + i * 256, bn1_m + i * 256, bn1_v + i * 256, y1);
        gemm_pw_kernel<<<dim3(512, 2), 256, 0, stream>>>(
            pwwb + i * 65536, y1, y0,
            pw_b + i * 256, bn2_g + i * 256, bn2_b + i * 256, bn2_m + i * 256, bn2_v + i * 256);
    }

    lstm_kernel<<<256, 256, 0, stream>>>(y0, lstm_w, lstm_b, Am);

    gemm_fc_kernel<<<832, 512, 0, stream>>>(Am, fcwb, fc_b, (float*)d_out);
}

// Round 15
// 650.196 us; speedup vs baseline: 1.0316x; 1.0316x over previous
//
#include <hip/hip_runtime.h>
#include <hip/hip_bf16.h>
#include <stdint.h>

#define BNEPS 1e-5f

typedef __bf16 bf16x8 __attribute__((ext_vector_type(8)));
typedef float f32x4 __attribute__((ext_vector_type(4)));
typedef unsigned short ushort8 __attribute__((ext_vector_type(8)));

__device__ __forceinline__ float gelu_f(float x) {
    return 0.5f * x * (1.0f + erff(x * 0.70710678118654752440f));
}
__device__ __forceinline__ float sigmoid_f(float x) {
    return 1.0f / (1.0f + __expf(-x));
}
__device__ __forceinline__ float tanh_f(float x) {
    x = fminf(fmaxf(x, -15.0f), 15.0f);
    const float e = __expf(2.0f * x);
    return (e - 1.0f) / (e + 1.0f);
}
__device__ __forceinline__ float bf2f(unsigned short u) {
    return __uint_as_float(((unsigned)u) << 16);
}
__device__ __forceinline__ void async16(const void* g, void* l) {
    __builtin_amdgcn_global_load_lds(
        (const __attribute__((address_space(1))) void*)g,
        (__attribute__((address_space(3))) void*)l,
        16, 0, 0);
}

// ---------------- stem: conv0 4x4/4 + BN0 + GELU -> y0 bf16 [32][256][8][256]
__global__ __launch_bounds__(256)
void stem_kernel(const float* __restrict__ x, const float* __restrict__ w,
                 const float* __restrict__ cb,
                 const float* __restrict__ bg, const float* __restrict__ bb,
                 const float* __restrict__ bm, const float* __restrict__ bv,
                 __hip_bfloat16* __restrict__ y0)
{
    __shared__ float sw[64 * 48];
    const int ho = blockIdx.x, b = blockIdx.y, co0 = blockIdx.z * 64;
    const int wo = threadIdx.x;
    for (int i = threadIdx.x; i < 64 * 48; i += 256) sw[i] = w[co0 * 48 + i];
    float p[48];
    #pragma unroll
    for (int c = 0; c < 3; ++c)
        #pragma unroll
        for (int kh = 0; kh < 4; ++kh) {
            const float4 q = *reinterpret_cast<const float4*>(
                &x[((size_t)(b * 3 + c) * 32 + ho * 4 + kh) * 1024 + wo * 4]);
            p[c * 16 + kh * 4 + 0] = q.x;
            p[c * 16 + kh * 4 + 1] = q.y;
            p[c * 16 + kh * 4 + 2] = q.z;
            p[c * 16 + kh * 4 + 3] = q.w;
        }
    __syncthreads();
    for (int c2 = 0; c2 < 64; ++c2) {
        const int co = co0 + c2;
        const float* wp = &sw[c2 * 48];
        float a0 = 0.f, a1 = 0.f, a2 = 0.f, a3 = 0.f;
        #pragma unroll
        for (int i = 0; i < 12; ++i) {
            const float4 wq = *reinterpret_cast<const float4*>(&wp[i * 4]);
            a0 += wq.x * p[i * 4 + 0];
            a1 += wq.y * p[i * 4 + 1];
            a2 += wq.z * p[i * 4 + 2];
            a3 += wq.w * p[i * 4 + 3];
        }
        const float acc = (a0 + a1) + (a2 + a3) + cb[co];
        const float sc = bg[co] / sqrtf(bv[co] + BNEPS);
        const float val = (acc - bm[co]) * sc + bb[co];
        y0[((size_t)(b * 256 + co) * 8 + ho) * 256 + wo] = __float2bfloat16(gelu_f(val));
    }
}

// ---------------- depthwise 3x3 + BN1 + GELU + residual: y0 bf16 -> y1 bf16 [b][c][8][256]
__global__ __launch_bounds__(256)
void dw_kernel(const __hip_bfloat16* __restrict__ y0, const float* __restrict__ dww,
               const float* __restrict__ dwb,
               const float* __restrict__ bg, const float* __restrict__ bb,
               const float* __restrict__ bm, const float* __restrict__ bv,
               __hip_bfloat16* __restrict__ y1)
{
    __shared__ float tile[8][258];
    const int c = blockIdx.x, b = blockIdx.y, t = threadIdx.x;
    const __hip_bfloat16* src = &y0[(size_t)(b * 256 + c) * 2048];
    {   // vectorized bf16x8 load: thread t covers flat elems [t*8, t*8+8)
        const ushort8 v = *reinterpret_cast<const ushort8*>(&src[t * 8]);
        const int r = t >> 5, c0 = (t & 31) * 8;
        #pragma unroll
        for (int i = 0; i < 8; ++i) tile[r][1 + c0 + i] = bf2f(v[i]);
    }
    if (t < 8) { tile[t][0] = 0.f; tile[t][257] = 0.f; }
    float w9[9];
    #pragma unroll
    for (int i = 0; i < 9; ++i) w9[i] = dww[c * 9 + i];
    const float bias = dwb[c];
    const float sc = bg[c] / sqrtf(bv[c] + BNEPS);
    const float sb = bb[c] - bm[c] * sc;
    __syncthreads();
    __hip_bfloat16* dst = &y1[(size_t)(b * 256 + c) * 2048];
    #pragma unroll
    for (int r = 0; r < 8; ++r) {
        float acc = bias;
        #pragma unroll
        for (int kh = 0; kh < 3; ++kh) {
            const int rr = r + kh - 1;
            if (rr < 0 || rr > 7) continue;
            acc += w9[kh * 3 + 0] * tile[rr][t] + w9[kh * 3 + 1] * tile[rr][t + 1]
                 + w9[kh * 3 + 2] * tile[rr][t + 2];
        }
        const float val = gelu_f(acc * sc + sb);
        dst[r * 256 + t] = __float2bfloat16(tile[r][t + 1] + val);
    }
}

// ---------------- pointwise GEMM with in-kernel B transpose (reg-staged).
// C[co][pos] = sum_ci W[co][ci] * y1[b][ci][pos]; BM=BN=128, BK=32, 4 waves.
// sB layout is the verified [128 pos][32 ci] (round-2); built by reg-staged
// transposed writes. Epilogue: bias+BN2+GELU -> y0 bf16 [b][co][hw].
__global__ __launch_bounds__(256)
void gemm_pw_kernel(const __hip_bfloat16* __restrict__ A,
                    const __hip_bfloat16* __restrict__ y1,
                    __hip_bfloat16* __restrict__ out,
                    const float* __restrict__ q0, const float* __restrict__ q1,
                    const float* __restrict__ q2, const float* __restrict__ q3,
                    const float* __restrict__ q4)
{
    __shared__ __hip_bfloat16 sA[2][4096];
    __shared__ __hip_bfloat16 sB[2][4096];
    const int tid = threadIdx.x;
    const int wave = tid >> 6, lane = tid & 63;
    const int m0 = blockIdx.y * 128, n0 = blockIdx.x * 128;
    const int b = n0 >> 11, hw0 = n0 & 2047;
    const __hip_bfloat16* ysrc = y1 + (size_t)b * 524288;   // [256 ci][2048 pos]

    const int ci2 = tid & 15, pos8 = tid >> 4;   // B-staging coords

    auto stageA = [&](int buf, int kt) {
        const int k0 = kt << 5;
        #pragma unroll
        for (int r = 0; r < 2; ++r) {
            const int e = wave * 1024 + r * 512 + lane * 8;
            const int row = e >> 5, ko = e & 31;
            async16(&A[(size_t)(m0 + row) * 256 + k0 + ko], &sA[buf][wave * 1024 + r * 512]);
        }
    };
    auto stageB = [&](int buf, int kt) {
        const int ci0 = kt << 5;
        const ushort8 u0 = *reinterpret_cast<const ushort8*>(
            &ysrc[(size_t)(ci0 + 2 * ci2) * 2048 + hw0 + pos8 * 8]);
        const ushort8 u1 = *reinterpret_cast<const ushort8*>(
            &ysrc[(size_t)(ci0 + 2 * ci2 + 1) * 2048 + hw0 + pos8 * 8]);
        #pragma unroll
        for (int j = 0; j < 8; ++j) {
            const unsigned pk = (unsigned)u0[j] | ((unsigned)u1[j] << 16);
            *reinterpret_cast<unsigned*>(&sB[buf][(pos8 * 8 + j) * 32 + 2 * ci2]) = pk;
        }
    };

    f32x4 acc[4][4];
    #pragma unroll
    for (int i = 0; i < 4; ++i)
        #pragma unroll
        for (int j = 0; j < 4; ++j) acc[i][j] = (f32x4){0.f, 0.f, 0.f, 0.f};

    stageA(0, 0); stageB(0, 0);
    const int wm = wave >> 1, wn = wave & 1;
    const int lrow = lane & 15, lgrp = lane >> 4;
    int cur = 0;
    for (int kt = 0; kt < 8; ++kt) {
        __syncthreads();   // drains vmcnt (A) + lgkm (B writes): buf[cur] ready
        if (kt + 1 < 8) { stageA(cur ^ 1, kt + 1); stageB(cur ^ 1, kt + 1); }
        bf16x8 av[4], bw[4];
        #pragma unroll
        for (int i = 0; i < 4; ++i) {
            av[i] = *reinterpret_cast<const bf16x8*>(&sA[cur][(wm * 64 + i * 16 + lrow) * 32 + lgrp * 8]);
            bw[i] = *reinterpret_cast<const bf16x8*>(&sB[cur][(wn * 64 + i * 16 + lrow) * 32 + lgrp * 8]);
        }
        #pragma unroll
        for (int mi = 0; mi < 4; ++mi)
            #pragma unroll
            for (int ni = 0; ni < 4; ++ni)
                acc[mi][ni] = __builtin_amdgcn_mfma_f32_16x16x32_bf16(av[mi], bw[ni], acc[mi][ni], 0, 0, 0);
        cur ^= 1;
    }

    #pragma unroll
    for (int mi = 0; mi < 4; ++mi) {
        const int rowb = m0 + wm * 64 + mi * 16 + lgrp * 4;
        #pragma unroll
        for (int ni = 0; ni < 4; ++ni) {
            const int hw = hw0 + wn * 64 + ni * 16 + lrow;
            #pragma unroll
            for (int r = 0; r < 4; ++r) {
                const float v = acc[mi][ni][r];
                const int co = rowb + r;
                const float sc = q1[co] / sqrtf(q4[co] + BNEPS);
                const float sb = q2[co] - q3[co] * sc;
                const float val = gelu_f((v + q0[co]) * sc + sb);
                out[((size_t)(b * 256 + co)) * 2048 + hw] = __float2bfloat16(val);
            }
        }
    }
}

// ---------------- FC GEMM: round-2 structure; XCD swizzle now m-fastest
// within each XCD (B-panel reused by 4 temporally-adjacent blocks from L2;
// the XCD's 4 A-panels stay L2-hot) to cut HBM re-fetch.
__global__ __launch_bounds__(512, 2)
void gemm_fc_kernel(const __hip_bfloat16* __restrict__ A,
                    const __hip_bfloat16* __restrict__ Bt,
                    const float* __restrict__ fcb,
                    float* __restrict__ out)
{
    constexpr int K = 2048, NT = 64, NTILE = 26;
    __shared__ __hip_bfloat16 smem[49152];
    const int tid = threadIdx.x, wave = tid >> 6, lane = tid & 63;
    const int wm = wave >> 2, wn = wave & 3;
    const int r = lane & 15, g = lane >> 4;
    const int swzk = (g ^ ((r >> 1) & 3)) * 8;

    const int bid = blockIdx.x;                 // 832 = 8 XCD x (4 m x 26 n)
    const int xcd = bid & 7, local = bid >> 3;  // local 0..103
    const int m0 = (xcd * 4 + (local & 3)) * 256;   // m fastest within XCD
    const int n0 = (local >> 2) * 256;

    auto stageA = [&](int buf, int kt) {
        #pragma unroll
        for (int r2 = 0; r2 < 2; ++r2) {
            const int e = wave * 128 + r2 * 64 + lane;
            const int row = e >> 2, slot = e & 3;
            const int kg = slot ^ ((row >> 1) & 3);
            async16(&A[(size_t)(m0 + row) * K + kt * 32 + kg * 8],
                    &smem[buf * 8192 + wave * 1024 + r2 * 512]);
        }
    };
    auto stageB = [&](int buf, int kt) {
        #pragma unroll
        for (int r2 = 0; r2 < 2; ++r2) {
            const int e = wave * 128 + r2 * 64 + lane;
            const int row = e >> 2, slot = e & 3;
            const int kg = slot ^ ((row >> 1) & 3);
            async16(&Bt[(size_t)(n0 + row) * K + kt * 32 + kg * 8],
                    &smem[24576 + buf * 8192 + wave * 1024 + r2 * 512]);
        }
    };

    f32x4 acc[8][4];
    #pragma unroll
    for (int i = 0; i < 8; ++i)
        #pragma unroll
        for (int j = 0; j < 4; ++j) acc[i][j] = (f32x4){0.f, 0.f, 0.f, 0.f};

    stageA(0, 0); stageB(0, 0);
    stageA(1, 1); stageB(1, 1);

    int bc = 0;
    for (int kt = 0; kt < NT; ++kt) {
        if (kt < NT - 1) asm volatile("s_waitcnt vmcnt(4)" ::: "memory");
        else             asm volatile("s_waitcnt vmcnt(0)" ::: "memory");
        asm volatile("s_barrier" ::: "memory");

        const int bn = (bc + 2 >= 3) ? bc - 1 : bc + 2;
        if (kt + 2 < NT) stageA(bn, kt + 2);

        const __hip_bfloat16* pA = &smem[bc * 8192];
        const __hip_bfloat16* pB = &smem[24576 + bc * 8192];
        bf16x8 av[8];
        #pragma unroll
        for (int mi = 0; mi < 8; ++mi)
            av[mi] = *reinterpret_cast<const bf16x8*>(&pA[(wm * 128 + mi * 16 + r) * 32 + swzk]);
        bf16x8 b0 = *reinterpret_cast<const bf16x8*>(&pB[(wn * 64 + 0 * 16 + r) * 32 + swzk]);
        bf16x8 b1 = *reinterpret_cast<const bf16x8*>(&pB[(wn * 64 + 1 * 16 + r) * 32 + swzk]);

        __builtin_amdgcn_s_setprio(1);
        #pragma unroll
        for (int mi = 0; mi < 8; ++mi) {
            acc[mi][0] = __builtin_amdgcn_mfma_f32_16x16x32_bf16(av[mi], b0, acc[mi][0], 0, 0, 0);
            acc[mi][1] = __builtin_amdgcn_mfma_f32_16x16x32_bf16(av[mi], b1, acc[mi][1], 0, 0, 0);
        }
        __builtin_amdgcn_s_setprio(0);

        if (kt + 2 < NT) stageB(bn, kt + 2);
        bf16x8 b2 = *reinterpret_cast<const bf16x8*>(&pB[(wn * 64 + 2 * 16 + r) * 32 + swzk]);
        bf16x8 b3 = *reinterpret_cast<const bf16x8*>(&pB[(wn * 64 + 3 * 16 + r) * 32 + swzk]);

        __builtin_amdgcn_s_setprio(1);
        #pragma unroll
        for (int mi = 0; mi < 8; ++mi) {
            acc[mi][2] = __builtin_amdgcn_mfma_f32_16x16x32_bf16(av[mi], b2, acc[mi][2], 0, 0, 0);
            acc[mi][3] = __builtin_amdgcn_mfma_f32_16x16x32_bf16(av[mi], b3, acc[mi][3], 0, 0, 0);
        }
        __builtin_amdgcn_s_setprio(0);

        bc = (bc == 2) ? 0 : bc + 1;
    }

    #pragma unroll
    for (int mi = 0; mi < 8; ++mi) {
        const int rowb = m0 + wm * 128 + mi * 16 + g * 4;
        #pragma unroll
        for (int ni = 0; ni < 4; ++ni) {
            const int col = n0 + wn * 64 + ni * 16 + r;
            if (col < 6625) {
                const float bb = fcb[col];
                #pragma unroll
                for (int rr = 0; rr < 4; ++rr)
                    out[(size_t)(rowb + rr) * 6625 + col] = acc[mi][ni][rr] + bb;
            }
        }
    }
}

// ---------------- ConvLSTM scan over t=channel (256 steps), y0 bf16 input
__global__ __launch_bounds__(256)
void lstm_kernel(const __hip_bfloat16* __restrict__ y, const float* __restrict__ lw,
                 const float* __restrict__ lb, __hip_bfloat16* __restrict__ Am)
{
    const int gid = blockIdx.x * 256 + threadIdx.x;     // 65536 threads
    const int f = gid & 7, pos = gid >> 3;
    const int l = pos & 255, b = pos >> 8;
    float W[4][16], bias[4];
    #pragma unroll
    for (int g = 0; g < 4; ++g) {
        #pragma unroll
        for (int j = 0; j < 16; ++j) W[g][j] = lw[(g * 8 + f) * 16 + j];
        bias[g] = lb[g * 8 + f];
    }
    float h = 0.f, c = 0.f;
    const __hip_bfloat16* xb = y + (size_t)b * 524288 + f * 256 + l;  // t-stride 2048
    __hip_bfloat16* ob = Am + (size_t)pos * 2048 + f;
    float xn = __bfloat162float(xb[0]);
    for (int t = 0; t < 256; ++t) {
        const float xt = xn;
        if (t < 255) xn = __bfloat162float(xb[(size_t)(t + 1) * 2048]);
        float A0 = bias[0], A1 = bias[1], A2 = bias[2], A3 = bias[3];
        #pragma unroll
        for (int j = 0; j < 8; ++j) {
            const float xj = __shfl(xt, j, 8);
            const float hj = __shfl(h, j, 8);
            A0 += W[0][j] * xj + W[0][8 + j] * hj;
            A1 += W[1][j] * xj + W[1][8 + j] * hj;
            A2 += W[2][j] * xj + W[2][8 + j] * hj;
            A3 += W[3][j] * xj + W[3][8 + j] * hj;
        }
        c = sigmoid_f(A1) * c + sigmoid_f(A0) * tanh_f(A3);   // af, ai, ag
        h = sigmoid_f(A2) * tanh_f(c);                        // ao
        ob[t * 8] = __float2bfloat16(h);
    }
}

// ---------------- converters
__global__ void cvt_pww_kernel(const float* __restrict__ w, __hip_bfloat16* __restrict__ o, int n)
{
    const int i = blockIdx.x * 256 + threadIdx.x;
    if (i < n) o[i] = __float2bfloat16(w[i]);
}
__global__ void cvt_fcw_kernel(const float* __restrict__ w, __hip_bfloat16* __restrict__ o)
{
    const size_t i4 = (size_t)blockIdx.x * 256 + threadIdx.x;   // over (6656*2048)/4
    const size_t base = i4 * 4;
    const size_t nrow = base >> 11, k = base & 2047;
    if (nrow < 6625) {
        const float4 q = *reinterpret_cast<const float4*>(&w[nrow * 2048 + k]);
        o[base + 0] = __float2bfloat16(q.x);
        o[base + 1] = __float2bfloat16(q.y);
        o[base + 2] = __float2bfloat16(q.z);
        o[base + 3] = __float2bfloat16(q.w);
    } else {
        o[base + 0] = __float2bfloat16(0.0f);
        o[base + 1] = __float2bfloat16(0.0f);
        o[base + 2] = __float2bfloat16(0.0f);
        o[base + 3] = __float2bfloat16(0.0f);
    }
}

extern "C" void kernel_launch(void* const* d_in, const int* in_sizes, int n_in,
                              void* d_out, int out_size, void* d_ws, size_t ws_size,
                              hipStream_t stream)
{
    const float* x       = (const float*)d_in[0];
    const float* conv0_w = (const float*)d_in[1];
    const float* conv0_b = (const float*)d_in[2];
    const float* bn0_g   = (const float*)d_in[3];
    const float* bn0_b   = (const float*)d_in[4];
    const float* bn0_m   = (const float*)d_in[5];
    const float* bn0_v   = (const float*)d_in[6];
    const float* dw_w    = (const float*)d_in[7];
    const float* dw_b    = (const float*)d_in[8];
    const float* bn1_g   = (const float*)d_in[9];
    const float* bn1_b   = (const float*)d_in[10];
    const float* bn1_m   = (const float*)d_in[11];
    const float* bn1_v   = (const float*)d_in[12];
    const float* pw_w    = (const float*)d_in[13];
    const float* pw_b    = (const float*)d_in[14];
    const float* bn2_g   = (const float*)d_in[15];
    const float* bn2_b   = (const float*)d_in[16];
    const float* bn2_m   = (const float*)d_in[17];
    const float* bn2_v   = (const float*)d_in[18];
    const float* lstm_w  = (const float*)d_in[19];
    const float* lstm_b  = (const float*)d_in[20];
    const float* fc_w    = (const float*)d_in[21];
    const float* fc_b    = (const float*)d_in[22];

    char* ws = (char*)d_ws;
    __hip_bfloat16* y0   = (__hip_bfloat16*)(ws);               // 33,554,432 B
    __hip_bfloat16* y1   = (__hip_bfloat16*)(ws + 33554432);    // 33,554,432 B
    __hip_bfloat16* Am   = (__hip_bfloat16*)(ws + 100663296);   // 33,554,432 B
    __hip_bfloat16* fcwb = (__hip_bfloat16*)(ws + 134217728);   // 27,262,976 B ([6656][2048])
    __hip_bfloat16* pwwb = (__hip_bfloat16*)(ws + 161480704);   //    524,288 B

    stem_kernel<<<dim3(8, 32, 4), 256, 0, stream>>>(
        x, conv0_w, conv0_b, bn0_g, bn0_b, bn0_m, bn0_v, y0);
    cvt_pww_kernel<<<1024, 256, 0, stream>>>(pw_w, pwwb, 262144);
    cvt_fcw_kernel<<<13312, 256, 0, stream>>>(fc_w, fcwb);

    for (int i = 0; i < 4; ++i) {
        dw_kernel<<<dim3(256, 32), 256, 0, stream>>>(
            y0, dw_w + i * 2304, dw_b + i * 256,
            bn1_g + i * 256, bn1_b + i * 256, bn1_m + i * 256, bn1_v + i * 256, y1);
        gemm_pw_kernel<<<dim3(512, 2), 256, 0, stream>>>(
            pwwb + i * 65536, y1, y0,
            pw_b + i * 256, bn2_g + i * 256, bn2_b + i * 256, bn2_m + i * 256, bn2_v + i * 256);
    }

    lstm_kernel<<<256, 256, 0, stream>>>(y0, lstm_w, lstm_b, Am);

    gemm_fc_kernel<<<832, 512, 0, stream>>>(Am, fcwb, fc_b, (float*)d_out);
}

// Round 16
// 643.306 us; speedup vs baseline: 1.0426x; 1.0107x over previous
//
#include <hip/hip_runtime.h>
#include <hip/hip_bf16.h>
#include <stdint.h>

#define BNEPS 1e-5f

typedef __bf16 bf16x8 __attribute__((ext_vector_type(8)));
typedef float f32x4 __attribute__((ext_vector_type(4)));
typedef unsigned short ushort8 __attribute__((ext_vector_type(8)));

__device__ __forceinline__ float gelu_f(float x) {
    return 0.5f * x * (1.0f + erff(x * 0.70710678118654752440f));
}
__device__ __forceinline__ float sigmoid_f(float x) {
    return 1.0f / (1.0f + __expf(-x));
}
__device__ __forceinline__ float tanh_f(float x) {
    x = fminf(fmaxf(x, -15.0f), 15.0f);
    const float e = __expf(2.0f * x);
    return (e - 1.0f) / (e + 1.0f);
}
__device__ __forceinline__ float bf2f(unsigned short u) {
    return __uint_as_float(((unsigned)u) << 16);
}
__device__ __forceinline__ void async16(const void* g, void* l) {
    __builtin_amdgcn_global_load_lds(
        (const __attribute__((address_space(1))) void*)g,
        (__attribute__((address_space(3))) void*)l,
        16, 0, 0);
}

// ---------------- stem: conv0 4x4/4 + BN0 + GELU -> y0 bf16 [32][256][8][256]
__global__ __launch_bounds__(256)
void stem_kernel(const float* __restrict__ x, const float* __restrict__ w,
                 const float* __restrict__ cb,
                 const float* __restrict__ bg, const float* __restrict__ bb,
                 const float* __restrict__ bm, const float* __restrict__ bv,
                 __hip_bfloat16* __restrict__ y0)
{
    __shared__ float sw[64 * 48];
    const int ho = blockIdx.x, b = blockIdx.y, co0 = blockIdx.z * 64;
    const int wo = threadIdx.x;
    for (int i = threadIdx.x; i < 64 * 48; i += 256) sw[i] = w[co0 * 48 + i];
    float p[48];
    #pragma unroll
    for (int c = 0; c < 3; ++c)
        #pragma unroll
        for (int kh = 0; kh < 4; ++kh) {
            const float4 q = *reinterpret_cast<const float4*>(
                &x[((size_t)(b * 3 + c) * 32 + ho * 4 + kh) * 1024 + wo * 4]);
            p[c * 16 + kh * 4 + 0] = q.x;
            p[c * 16 + kh * 4 + 1] = q.y;
            p[c * 16 + kh * 4 + 2] = q.z;
            p[c * 16 + kh * 4 + 3] = q.w;
        }
    __syncthreads();
    for (int c2 = 0; c2 < 64; ++c2) {
        const int co = co0 + c2;
        const float* wp = &sw[c2 * 48];
        float a0 = 0.f, a1 = 0.f, a2 = 0.f, a3 = 0.f;
        #pragma unroll
        for (int i = 0; i < 12; ++i) {
            const float4 wq = *reinterpret_cast<const float4*>(&wp[i * 4]);
            a0 += wq.x * p[i * 4 + 0];
            a1 += wq.y * p[i * 4 + 1];
            a2 += wq.z * p[i * 4 + 2];
            a3 += wq.w * p[i * 4 + 3];
        }
        const float acc = (a0 + a1) + (a2 + a3) + cb[co];
        const float sc = bg[co] / sqrtf(bv[co] + BNEPS);
        const float val = (acc - bm[co]) * sc + bb[co];
        y0[((size_t)(b * 256 + co) * 8 + ho) * 256 + wo] = __float2bfloat16(gelu_f(val));
    }
}

// ---------------- depthwise 3x3 + BN1 + GELU + residual: y0 bf16 -> y1 bf16 [b][c][8][256]
__global__ __launch_bounds__(256)
void dw_kernel(const __hip_bfloat16* __restrict__ y0, const float* __restrict__ dww,
               const float* __restrict__ dwb,
               const float* __restrict__ bg, const float* __restrict__ bb,
               const float* __restrict__ bm, const float* __restrict__ bv,
               __hip_bfloat16* __restrict__ y1)
{
    __shared__ float tile[8][258];
    const int c = blockIdx.x, b = blockIdx.y, t = threadIdx.x;
    const __hip_bfloat16* src = &y0[(size_t)(b * 256 + c) * 2048];
    {   // vectorized bf16x8 load: thread t covers flat elems [t*8, t*8+8)
        const ushort8 v = *reinterpret_cast<const ushort8*>(&src[t * 8]);
        const int r = t >> 5, c0 = (t & 31) * 8;
        #pragma unroll
        for (int i = 0; i < 8; ++i) tile[r][1 + c0 + i] = bf2f(v[i]);
    }
    if (t < 8) { tile[t][0] = 0.f; tile[t][257] = 0.f; }
    float w9[9];
    #pragma unroll
    for (int i = 0; i < 9; ++i) w9[i] = dww[c * 9 + i];
    const float bias = dwb[c];
    const float sc = bg[c] / sqrtf(bv[c] + BNEPS);
    const float sb = bb[c] - bm[c] * sc;
    __syncthreads();
    __hip_bfloat16* dst = &y1[(size_t)(b * 256 + c) * 2048];
    #pragma unroll
    for (int r = 0; r < 8; ++r) {
        float acc = bias;
        #pragma unroll
        for (int kh = 0; kh < 3; ++kh) {
            const int rr = r + kh - 1;
            if (rr < 0 || rr > 7) continue;
            acc += w9[kh * 3 + 0] * tile[rr][t] + w9[kh * 3 + 1] * tile[rr][t + 1]
                 + w9[kh * 3 + 2] * tile[rr][t + 2];
        }
        const float val = gelu_f(acc * sc + sb);
        dst[r * 256 + t] = __float2bfloat16(tile[r][t + 1] + val);
    }
}

// ---------------- pointwise GEMM with in-kernel B transpose (reg-staged).
// C[co][pos] = sum_ci W[co][ci] * y1[b][ci][pos]; BM=BN=128, BK=32, 4 waves.
// sB layout is the verified [128 pos][32 ci] (round-2); built by reg-staged
// transposed writes. Epilogue: bias+BN2+GELU -> y0 bf16 [b][co][hw].
__global__ __launch_bounds__(256)
void gemm_pw_kernel(const __hip_bfloat16* __restrict__ A,
                    const __hip_bfloat16* __restrict__ y1,
                    __hip_bfloat16* __restrict__ out,
                    const float* __restrict__ q0, const float* __restrict__ q1,
                    const float* __restrict__ q2, const float* __restrict__ q3,
                    const float* __restrict__ q4)
{
    __shared__ __hip_bfloat16 sA[2][4096];
    __shared__ __hip_bfloat16 sB[2][4096];
    const int tid = threadIdx.x;
    const int wave = tid >> 6, lane = tid & 63;
    const int m0 = blockIdx.y * 128, n0 = blockIdx.x * 128;
    const int b = n0 >> 11, hw0 = n0 & 2047;
    const __hip_bfloat16* ysrc = y1 + (size_t)b * 524288;   // [256 ci][2048 pos]

    const int ci2 = tid & 15, pos8 = tid >> 4;   // B-staging coords

    auto stageA = [&](int buf, int kt) {
        const int k0 = kt << 5;
        #pragma unroll
        for (int r = 0; r < 2; ++r) {
            const int e = wave * 1024 + r * 512 + lane * 8;
            const int row = e >> 5, ko = e & 31;
            async16(&A[(size_t)(m0 + row) * 256 + k0 + ko], &sA[buf][wave * 1024 + r * 512]);
        }
    };
    auto stageB = [&](int buf, int kt) {
        const int ci0 = kt << 5;
        const ushort8 u0 = *reinterpret_cast<const ushort8*>(
            &ysrc[(size_t)(ci0 + 2 * ci2) * 2048 + hw0 + pos8 * 8]);
        const ushort8 u1 = *reinterpret_cast<const ushort8*>(
            &ysrc[(size_t)(ci0 + 2 * ci2 + 1) * 2048 + hw0 + pos8 * 8]);
        #pragma unroll
        for (int j = 0; j < 8; ++j) {
            const unsigned pk = (unsigned)u0[j] | ((unsigned)u1[j] << 16);
            *reinterpret_cast<unsigned*>(&sB[buf][(pos8 * 8 + j) * 32 + 2 * ci2]) = pk;
        }
    };

    f32x4 acc[4][4];
    #pragma unroll
    for (int i = 0; i < 4; ++i)
        #pragma unroll
        for (int j = 0; j < 4; ++j) acc[i][j] = (f32x4){0.f, 0.f, 0.f, 0.f};

    stageA(0, 0); stageB(0, 0);
    const int wm = wave >> 1, wn = wave & 1;
    const int lrow = lane & 15, lgrp = lane >> 4;
    int cur = 0;
    for (int kt = 0; kt < 8; ++kt) {
        __syncthreads();   // drains vmcnt (A) + lgkm (B writes): buf[cur] ready
        if (kt + 1 < 8) { stageA(cur ^ 1, kt + 1); stageB(cur ^ 1, kt + 1); }
        bf16x8 av[4], bw[4];
        #pragma unroll
        for (int i = 0; i < 4; ++i) {
            av[i] = *reinterpret_cast<const bf16x8*>(&sA[cur][(wm * 64 + i * 16 + lrow) * 32 + lgrp * 8]);
            bw[i] = *reinterpret_cast<const bf16x8*>(&sB[cur][(wn * 64 + i * 16 + lrow) * 32 + lgrp * 8]);
        }
        #pragma unroll
        for (int mi = 0; mi < 4; ++mi)
            #pragma unroll
            for (int ni = 0; ni < 4; ++ni)
                acc[mi][ni] = __builtin_amdgcn_mfma_f32_16x16x32_bf16(av[mi], bw[ni], acc[mi][ni], 0, 0, 0);
        cur ^= 1;
    }

    #pragma unroll
    for (int mi = 0; mi < 4; ++mi) {
        const int rowb = m0 + wm * 64 + mi * 16 + lgrp * 4;
        #pragma unroll
        for (int ni = 0; ni < 4; ++ni) {
            const int hw = hw0 + wn * 64 + ni * 16 + lrow;
            #pragma unroll
            for (int r = 0; r < 4; ++r) {
                const float v = acc[mi][ni][r];
                const int co = rowb + r;
                const float sc = q1[co] / sqrtf(q4[co] + BNEPS);
                const float sb = q2[co] - q3[co] * sc;
                const float val = gelu_f((v + q0[co]) * sc + sb);
                out[((size_t)(b * 256 + co)) * 2048 + hw] = __float2bfloat16(val);
            }
        }
    }
}

// ---------------- FC GEMM: round-2 structure (session-best, 257 us / 866 TF).
// 256x256 tile, BK=32, 8 waves, 3 LDS buffers (96 KB), depth-2 prefetch,
// counted vmcnt(4), T1 XCD swizzle (n-fastest), T2 LDS XOR-swizzle, T5 setprio.
__global__ __launch_bounds__(512, 2)
void gemm_fc_kernel(const __hip_bfloat16* __restrict__ A,
                    const __hip_bfloat16* __restrict__ Bt,
                    const float* __restrict__ fcb,
                    float* __restrict__ out)
{
    constexpr int K = 2048, NT = 64, NTILE = 26;
    __shared__ __hip_bfloat16 smem[49152];
    const int tid = threadIdx.x, wave = tid >> 6, lane = tid & 63;
    const int wm = wave >> 2, wn = wave & 3;
    const int r = lane & 15, g = lane >> 4;
    const int swzk = (g ^ ((r >> 1) & 3)) * 8;

    const int bid = blockIdx.x;
    const int swz = (bid & 7) * 104 + (bid >> 3);
    const int m0 = (swz / NTILE) * 256;
    const int n0 = (swz % NTILE) * 256;

    auto stageA = [&](int buf, int kt) {
        #pragma unroll
        for (int r2 = 0; r2 < 2; ++r2) {
            const int e = wave * 128 + r2 * 64 + lane;
            const int row = e >> 2, slot = e & 3;
            const int kg = slot ^ ((row >> 1) & 3);
            async16(&A[(size_t)(m0 + row) * K + kt * 32 + kg * 8],
                    &smem[buf * 8192 + wave * 1024 + r2 * 512]);
        }
    };
    auto stageB = [&](int buf, int kt) {
        #pragma unroll
        for (int r2 = 0; r2 < 2; ++r2) {
            const int e = wave * 128 + r2 * 64 + lane;
            const int row = e >> 2, slot = e & 3;
            const int kg = slot ^ ((row >> 1) & 3);
            async16(&Bt[(size_t)(n0 + row) * K + kt * 32 + kg * 8],
                    &smem[24576 + buf * 8192 + wave * 1024 + r2 * 512]);
        }
    };

    f32x4 acc[8][4];
    #pragma unroll
    for (int i = 0; i < 8; ++i)
        #pragma unroll
        for (int j = 0; j < 4; ++j) acc[i][j] = (f32x4){0.f, 0.f, 0.f, 0.f};

    stageA(0, 0); stageB(0, 0);
    stageA(1, 1); stageB(1, 1);

    int bc = 0;
    for (int kt = 0; kt < NT; ++kt) {
        if (kt < NT - 1) asm volatile("s_waitcnt vmcnt(4)" ::: "memory");
        else             asm volatile("s_waitcnt vmcnt(0)" ::: "memory");
        asm volatile("s_barrier" ::: "memory");

        const int bn = (bc + 2 >= 3) ? bc - 1 : bc + 2;
        if (kt + 2 < NT) stageA(bn, kt + 2);

        const __hip_bfloat16* pA = &smem[bc * 8192];
        const __hip_bfloat16* pB = &smem[24576 + bc * 8192];
        bf16x8 av[8];
        #pragma unroll
        for (int mi = 0; mi < 8; ++mi)
            av[mi] = *reinterpret_cast<const bf16x8*>(&pA[(wm * 128 + mi * 16 + r) * 32 + swzk]);
        bf16x8 b0 = *reinterpret_cast<const bf16x8*>(&pB[(wn * 64 + 0 * 16 + r) * 32 + swzk]);
        bf16x8 b1 = *reinterpret_cast<const bf16x8*>(&pB[(wn * 64 + 1 * 16 + r) * 32 + swzk]);

        __builtin_amdgcn_s_setprio(1);
        #pragma unroll
        for (int mi = 0; mi < 8; ++mi) {
            acc[mi][0] = __builtin_amdgcn_mfma_f32_16x16x32_bf16(av[mi], b0, acc[mi][0], 0, 0, 0);
            acc[mi][1] = __builtin_amdgcn_mfma_f32_16x16x32_bf16(av[mi], b1, acc[mi][1], 0, 0, 0);
        }
        __builtin_amdgcn_s_setprio(0);

        if (kt + 2 < NT) stageB(bn, kt + 2);
        bf16x8 b2 = *reinterpret_cast<const bf16x8*>(&pB[(wn * 64 + 2 * 16 + r) * 32 + swzk]);
        bf16x8 b3 = *reinterpret_cast<const bf16x8*>(&pB[(wn * 64 + 3 * 16 + r) * 32 + swzk]);

        __builtin_amdgcn_s_setprio(1);
        #pragma unroll
        for (int mi = 0; mi < 8; ++mi) {
            acc[mi][2] = __builtin_amdgcn_mfma_f32_16x16x32_bf16(av[mi], b2, acc[mi][2], 0, 0, 0);
            acc[mi][3] = __builtin_amdgcn_mfma_f32_16x16x32_bf16(av[mi], b3, acc[mi][3], 0, 0, 0);
        }
        __builtin_amdgcn_s_setprio(0);

        bc = (bc == 2) ? 0 : bc + 1;
    }

    #pragma unroll
    for (int mi = 0; mi < 8; ++mi) {
        const int rowb = m0 + wm * 128 + mi * 16 + g * 4;
        #pragma unroll
        for (int ni = 0; ni < 4; ++ni) {
            const int col = n0 + wn * 64 + ni * 16 + r;
            if (col < 6625) {
                const float bb = fcb[col];
                #pragma unroll
                for (int rr = 0; rr < 4; ++rr)
                    out[(size_t)(rowb + rr) * 6625 + col] = acc[mi][ni][rr] + bb;
            }
        }
    }
}

// ---------------- ConvLSTM scan over t=channel (256 steps), y0 bf16 input
__global__ __launch_bounds__(256)
void lstm_kernel(const __hip_bfloat16* __restrict__ y, const float* __restrict__ lw,
                 const float* __restrict__ lb, __hip_bfloat16* __restrict__ Am)
{
    const int gid = blockIdx.x * 256 + threadIdx.x;     // 65536 threads
    const int f = gid & 7, pos = gid >> 3;
    const int l = pos & 255, b = pos >> 8;
    float W[4][16], bias[4];
    #pragma unroll
    for (int g = 0; g < 4; ++g) {
        #pragma unroll
        for (int j = 0; j < 16; ++j) W[g][j] = lw[(g * 8 + f) * 16 + j];
        bias[g] = lb[g * 8 + f];
    }
    float h = 0.f, c = 0.f;
    const __hip_bfloat16* xb = y + (size_t)b * 524288 + f * 256 + l;  // t-stride 2048
    __hip_bfloat16* ob = Am + (size_t)pos * 2048 + f;
    float xn = __bfloat162float(xb[0]);
    for (int t = 0; t < 256; ++t) {
        const float xt = xn;
        if (t < 255) xn = __bfloat162float(xb[(size_t)(t + 1) * 2048]);
        float A0 = bias[0], A1 = bias[1], A2 = bias[2], A3 = bias[3];
        #pragma unroll
        for (int j = 0; j < 8; ++j) {
            const float xj = __shfl(xt, j, 8);
            const float hj = __shfl(h, j, 8);
            A0 += W[0][j] * xj + W[0][8 + j] * hj;
            A1 += W[1][j] * xj + W[1][8 + j] * hj;
            A2 += W[2][j] * xj + W[2][8 + j] * hj;
            A3 += W[3][j] * xj + W[3][8 + j] * hj;
        }
        c = sigmoid_f(A1) * c + sigmoid_f(A0) * tanh_f(A3);   // af, ai, ag
        h = sigmoid_f(A2) * tanh_f(c);                        // ao
        ob[t * 8] = __float2bfloat16(h);
    }
}

// ---------------- converters
__global__ void cvt_pww_kernel(const float* __restrict__ w, __hip_bfloat16* __restrict__ o, int n)
{
    const int i = blockIdx.x * 256 + threadIdx.x;
    if (i < n) o[i] = __float2bfloat16(w[i]);
}
__global__ void cvt_fcw_kernel(const float* __restrict__ w, __hip_bfloat16* __restrict__ o)
{
    const size_t i4 = (size_t)blockIdx.x * 256 + threadIdx.x;   // over (6656*2048)/4
    const size_t base = i4 * 4;
    const size_t nrow = base >> 11, k = base & 2047;
    if (nrow < 6625) {
        const float4 q = *reinterpret_cast<const float4*>(&w[nrow * 2048 + k]);
        o[base + 0] = __float2bfloat16(q.x);
        o[base + 1] = __float2bfloat16(q.y);
        o[base + 2] = __float2bfloat16(q.z);
        o[base + 3] = __float2bfloat16(q.w);
    } else {
        o[base + 0] = __float2bfloat16(0.0f);
        o[base + 1] = __float2bfloat16(0.0f);
        o[base + 2] = __float2bfloat16(0.0f);
        o[base + 3] = __float2bfloat16(0.0f);
    }
}

extern "C" void kernel_launch(void* const* d_in, const int* in_sizes, int n_in,
                              void* d_out, int out_size, void* d_ws, size_t ws_size,
                              hipStream_t stream)
{
    const float* x       = (const float*)d_in[0];
    const float* conv0_w = (const float*)d_in[1];
    const float* conv0_b = (const float*)d_in[2];
    const float* bn0_g   = (const float*)d_in[3];
    const float* bn0_b   = (const float*)d_in[4];
    const float* bn0_m   = (const float*)d_in[5];
    const float* bn0_v   = (const float*)d_in[6];
    const float* dw_w    = (const float*)d_in[7];
    const float* dw_b    = (const float*)d_in[8];
    const float* bn1_g   = (const float*)d_in[9];
    const float* bn1_b   = (const float*)d_in[10];
    const float* bn1_m   = (const float*)d_in[11];
    const float* bn1_v   = (const float*)d_in[12];
    const float* pw_w    = (const float*)d_in[13];
    const float* pw_b    = (const float*)d_in[14];
    const float* bn2_g   = (const float*)d_in[15];
    const float* bn2_b   = (const float*)d_in[16];
    const float* bn2_m   = (const float*)d_in[17];
    const float* bn2_v   = (const float*)d_in[18];
    const float* lstm_w  = (const float*)d_in[19];
    const float* lstm_b  = (const float*)d_in[20];
    const float* fc_w    = (const float*)d_in[21];
    const float* fc_b    = (const float*)d_in[22];

    char* ws = (char*)d_ws;
    __hip_bfloat16* y0   = (__hip_bfloat16*)(ws);               // 33,554,432 B
    __hip_bfloat16* y1   = (__hip_bfloat16*)(ws + 33554432);    // 33,554,432 B
    __hip_bfloat16* Am   = (__hip_bfloat16*)(ws + 100663296);   // 33,554,432 B
    __hip_bfloat16* fcwb = (__hip_bfloat16*)(ws + 134217728);   // 27,262,976 B ([6656][2048])
    __hip_bfloat16* pwwb = (__hip_bfloat16*)(ws + 161480704);   //    524,288 B

    stem_kernel<<<dim3(8, 32, 4), 256, 0, stream>>>(
        x, conv0_w, conv0_b, bn0_g, bn0_b, bn0_m, bn0_v, y0);
    cvt_pww_kernel<<<1024, 256, 0, stream>>>(pw_w, pwwb, 262144);
    cvt_fcw_kernel<<<13312, 256, 0, stream>>>(fc_w, fcwb);

    for (int i = 0; i < 4; ++i) {
        dw_kernel<<<dim3(256, 32), 256, 0, stream>>>(
            y0, dw_w + i * 2304, dw_b + i * 256,
            bn1_g + i * 256, bn1_b + i * 256, bn1_m + i * 256, bn1_v + i * 256, y1);
        gemm_pw_kernel<<<dim3(512, 2), 256, 0, stream>>>(
            pwwb + i * 65536, y1, y0,
            pw_b + i * 256, bn2_g + i * 256, bn2_b + i * 256, bn2_m + i * 256, bn2_v + i * 256);
    }

    lstm_kernel<<<256, 256, 0, stream>>>(y0, lstm_w, lstm_b, Am);

    gemm_fc_kernel<<<832, 512, 0, stream>>>(Am, fcwb, fc_b, (float*)d_out);
}